// Round 11
// baseline (481.586 us; speedup 1.0000x reference)
//
#include <hip/hip_runtime.h>

#define SB 2
#define HH 8
#define SS 2048
#define DM 512
#define HD 64
#define SCALE 0.125f
#define ETP 2056   // e_tile row stride (u16), +8 pad breaks bank alignment

typedef __attribute__((ext_vector_type(8))) short bfrag;   // 8 x bf16
typedef __attribute__((ext_vector_type(4))) float f4;

static __device__ __forceinline__ unsigned short f2bf(float x) {
  unsigned int u = __float_as_uint(x);
  unsigned int r = (u + 0x7FFFu + ((u >> 16) & 1u)) >> 16;
  return (unsigned short)r;
}
static __device__ __forceinline__ float bf2f(unsigned short s) {
  return __uint_as_float(((unsigned int)s) << 16);
}
static __device__ __forceinline__ void splitf(float x, short& hi, short& lo) {
  const unsigned u = __float_as_uint(x);
  hi = (short)(u >> 16);                                    // truncation
  lo = (short)f2bf(x - __uint_as_float(u & 0xFFFF0000u));   // RTNE residual
}

// async global -> LDS DMA, 16 B per lane (dest = uniform base + lane*16)
static __device__ __forceinline__ void dma16(const unsigned short* g,
                                             unsigned short* l) {
  __builtin_amdgcn_global_load_lds(
      (const __attribute__((address_space(1))) void*)g,
      (__attribute__((address_space(3))) void*)l, 16, 0, 0);
}

// ---------------- generic fp32 GEMM: C[M][N] = A[M][K] @ B[K][N] (+bias) ---
__global__ __launch_bounds__(256) void gemm_f32(const float* __restrict__ A,
                                                const float* __restrict__ Bm,
                                                const float* __restrict__ bias,
                                                float* __restrict__ C,
                                                int M, int N, int K) {
  __shared__ float As[16][68];
  __shared__ float Bs[16][64];
  const int t = threadIdx.x;
  const int nb = N >> 6;
  const int bm = blockIdx.x / nb, bn = blockIdx.x % nb;
  const int m0 = bm << 6, n0 = bn << 6;
  const int ty = t >> 4, tx = t & 15;
  const int mr = ty << 2, nc = tx << 2;
  const int am = t >> 2, akq = t & 3;
  const int bk = t >> 4, bnq = t & 15;
  float acc[4][4] = {};
  for (int k0 = 0; k0 < K; k0 += 16) {
    const float4 av = *(const float4*)&A[(size_t)(m0 + am) * K + k0 + (akq << 2)];
    const float4 bv = *(const float4*)&Bm[(size_t)(k0 + bk) * N + n0 + (bnq << 2)];
    __syncthreads();
    As[(akq << 2) + 0][am] = av.x;
    As[(akq << 2) + 1][am] = av.y;
    As[(akq << 2) + 2][am] = av.z;
    As[(akq << 2) + 3][am] = av.w;
    *(float4*)&Bs[bk][bnq << 2] = bv;
    __syncthreads();
#pragma unroll
    for (int kk = 0; kk < 16; ++kk) {
      float a[4], b[4];
      *(float4*)a = *(const float4*)&As[kk][mr];
      *(float4*)b = *(const float4*)&Bs[kk][nc];
#pragma unroll
      for (int i = 0; i < 4; ++i)
#pragma unroll
        for (int j = 0; j < 4; ++j) acc[i][j] += a[i] * b[j];
    }
  }
#pragma unroll
  for (int i = 0; i < 4; ++i) {
    float4 v = make_float4(acc[i][0], acc[i][1], acc[i][2], acc[i][3]);
    if (bias) {
      v.x += bias[n0 + nc + 0];
      v.y += bias[n0 + nc + 1];
      v.z += bias[n0 + nc + 2];
      v.w += bias[n0 + nc + 3];
    }
    *(float4*)&C[(size_t)(m0 + mr + i) * N + n0 + nc] = v;
  }
}

// -------- gemm_f32_vt: same compute, epilogue writes per-head transposed ---
__global__ __launch_bounds__(256) void gemm_f32_vt(const float* __restrict__ A,
                                                   const float* __restrict__ Bm,
                                                   unsigned short* __restrict__ VT,
                                                   int M, int N, int K) {
  __shared__ float As[16][68];
  __shared__ float Bs[16][64];
  const int t = threadIdx.x;
  const int nb = N >> 6;
  const int bm = blockIdx.x / nb, bn = blockIdx.x % nb;
  const int m0 = bm << 6, n0 = bn << 6;
  const int ty = t >> 4, tx = t & 15;
  const int mr = ty << 2, nc = tx << 2;
  const int am = t >> 2, akq = t & 3;
  const int bk = t >> 4, bnq = t & 15;
  float acc[4][4] = {};
  for (int k0 = 0; k0 < K; k0 += 16) {
    const float4 av = *(const float4*)&A[(size_t)(m0 + am) * K + k0 + (akq << 2)];
    const float4 bv = *(const float4*)&Bm[(size_t)(k0 + bk) * N + n0 + (bnq << 2)];
    __syncthreads();
    As[(akq << 2) + 0][am] = av.x;
    As[(akq << 2) + 1][am] = av.y;
    As[(akq << 2) + 2][am] = av.z;
    As[(akq << 2) + 3][am] = av.w;
    *(float4*)&Bs[bk][bnq << 2] = bv;
    __syncthreads();
#pragma unroll
    for (int kk = 0; kk < 16; ++kk) {
      float a[4], b[4];
      *(float4*)a = *(const float4*)&As[kk][mr];
      *(float4*)b = *(const float4*)&Bs[kk][nc];
#pragma unroll
      for (int i = 0; i < 4; ++i)
#pragma unroll
        for (int j = 0; j < 4; ++j) acc[i][j] += a[i] * b[j];
    }
  }
#pragma unroll
  for (int i = 0; i < 4; ++i) {
    const int row = m0 + mr + i;
    const int bb = row >> 11, jr = row & 2047;
#pragma unroll
    for (int jx = 0; jx < 4; ++jx) {
      const int col = n0 + nc + jx;
      const int bh = bb * HH + (col >> 6), d = col & 63;
      VT[((size_t)bh * HD + d) * SS + jr] = f2bf(acc[i][jx]);
    }
  }
}

// -------- gemm_f32_khl: K projection, epilogue writes per-head hi/lo bf16 --
__global__ __launch_bounds__(256) void gemm_f32_khl(const float* __restrict__ A,
                                                    const float* __restrict__ Bm,
                                                    unsigned short* __restrict__ kh,
                                                    unsigned short* __restrict__ kl,
                                                    int M, int N, int K) {
  __shared__ float As[16][68];
  __shared__ float Bs[16][64];
  const int t = threadIdx.x;
  const int nb = N >> 6;
  const int bm = blockIdx.x / nb, bn = blockIdx.x % nb;
  const int m0 = bm << 6, n0 = bn << 6;
  const int ty = t >> 4, tx = t & 15;
  const int mr = ty << 2, nc = tx << 2;
  const int am = t >> 2, akq = t & 3;
  const int bk = t >> 4, bnq = t & 15;
  float acc[4][4] = {};
  for (int k0 = 0; k0 < K; k0 += 16) {
    const float4 av = *(const float4*)&A[(size_t)(m0 + am) * K + k0 + (akq << 2)];
    const float4 bv = *(const float4*)&Bm[(size_t)(k0 + bk) * N + n0 + (bnq << 2)];
    __syncthreads();
    As[(akq << 2) + 0][am] = av.x;
    As[(akq << 2) + 1][am] = av.y;
    As[(akq << 2) + 2][am] = av.z;
    As[(akq << 2) + 3][am] = av.w;
    *(float4*)&Bs[bk][bnq << 2] = bv;
    __syncthreads();
#pragma unroll
    for (int kk = 0; kk < 16; ++kk) {
      float a[4], b[4];
      *(float4*)a = *(const float4*)&As[kk][mr];
      *(float4*)b = *(const float4*)&Bs[kk][nc];
#pragma unroll
      for (int i = 0; i < 4; ++i)
#pragma unroll
        for (int j = 0; j < 4; ++j) acc[i][j] += a[i] * b[j];
    }
  }
#pragma unroll
  for (int i = 0; i < 4; ++i) {
    const int row = m0 + mr + i;
    const int bb = row >> 11, jr = row & 2047;
#pragma unroll
    for (int jx = 0; jx < 4; ++jx) {
      const int col = n0 + nc + jx;
      const int bh = bb * HH + (col >> 6), d = col & 63;
      short hi, lo;
      splitf(acc[i][jx], hi, lo);
      const size_t o = ((size_t)bh * SS + jr) * HD + d;
      kh[o] = (unsigned short)hi;
      kl[o] = (unsigned short)lo;
    }
  }
}

// ---------------------------------------------------------------------------
// prep_evt: Ev fp32 [513][64] -> EvT bf16 [64][544] (transposed, zero-padded).
// ---------------------------------------------------------------------------
__global__ void prep_evt(const float* __restrict__ Ev, unsigned short* __restrict__ EvT) {
  const int idx = blockIdx.x * 256 + threadIdx.x;
  if (idx >= 64 * 544) return;
  const int d = idx / 544, r = idx % 544;
  EvT[idx] = (r < 513) ? f2bf(Ev[(size_t)r * HD + d]) : (unsigned short)0;
}

// ---------------------------------------------------------------------------
// fused_attn9: SINGLE-sweep, DMA-paced, e-in-LDS attention.
// Per 64-j tile: issue DMA(t+1) -> compute QK^T(t) -> e=exp(l) (bf16) into
// persistent e_tile -> ONE barrier (DMA flown behind compute) -> PV from
// e_tile (unnormalized) with V direct from L2-resident global.
// Epilogue: z/bins merge; coalesced NT writeback w = e*zi from e_tile; band
// GEMM reads e_tile directly (bins folded), result scaled by row-uniform zi.
// 116 KB LDS -> 1 block/CU; launch_bounds(256,1) gives full VGPR headroom.
// ---------------------------------------------------------------------------
#define QK6(K0, K1, L0, L1, ACC)                                            \
  ACC = __builtin_amdgcn_mfma_f32_16x16x32_bf16(qh0, K0, ACC, 0, 0, 0);     \
  ACC = __builtin_amdgcn_mfma_f32_16x16x32_bf16(qh1, K1, ACC, 0, 0, 0);     \
  ACC = __builtin_amdgcn_mfma_f32_16x16x32_bf16(ql0, K0, ACC, 0, 0, 0);     \
  ACC = __builtin_amdgcn_mfma_f32_16x16x32_bf16(ql1, K1, ACC, 0, 0, 0);     \
  ACC = __builtin_amdgcn_mfma_f32_16x16x32_bf16(qh0, L0, ACC, 0, 0, 0);     \
  ACC = __builtin_amdgcn_mfma_f32_16x16x32_bf16(qh1, L1, ACC, 0, 0, 0);

__global__ __launch_bounds__(256, 1) void fused_attn9(
    const float* __restrict__ Qp,
    const unsigned short* __restrict__ khg,
    const unsigned short* __restrict__ klg,
    const unsigned short* __restrict__ VTg,
    const float* __restrict__ Ek,
    const unsigned short* __restrict__ EvT,
    float* __restrict__ attn,
    float* __restrict__ concat) {
  __shared__ __attribute__((aligned(16))) unsigned short e_tile[16][ETP];  // 65792
  __shared__ __attribute__((aligned(16))) unsigned short qek_lds[16][520]; // 16640
  __shared__ __attribute__((aligned(16))) unsigned short kbh[2][64][64];   // 16384
  __shared__ __attribute__((aligned(16))) unsigned short kbl[2][64][64];   // 16384
  __shared__ float zb[4][16];
  __shared__ float lhb[4][16][2];
  __shared__ float lhm[16][2];

  const int t = threadIdx.x;
  const int orig = blockIdx.x;
  const int wg = (orig & 7) * 256 + (orig >> 3);   // XCD swizzle (bijective)
  const int bh = wg >> 7, rb = wg & 127;
  const int b = bh >> 3, h = bh & 7;
  const int wv = t >> 6, lane = t & 63;
  const int ln = lane & 15, lq = lane >> 4;
  const int i0 = rb * 16;

  // Q fragments hi/lo (block's 16 rows, same for all waves)
  bfrag qh0, qh1, ql0, ql1;
  {
    const float* qrow = Qp + (size_t)(b * SS + i0 + ln) * DM + h * HD + lq * 8;
    const f4 x0 = *(const f4*)&qrow[0], x1 = *(const f4*)&qrow[4];
    const f4 x2 = *(const f4*)&qrow[32], x3 = *(const f4*)&qrow[36];
#pragma unroll
    for (int e = 0; e < 4; ++e) {
      short hi, lo;
      splitf(x0[e], hi, lo); qh0[e] = hi; ql0[e] = lo;
      splitf(x1[e], hi, lo); qh0[e + 4] = hi; ql0[e + 4] = lo;
      splitf(x2[e], hi, lo); qh1[e] = hi; ql1[e] = lo;
      splitf(x3[e], hi, lo); qh1[e + 4] = hi; ql1[e + 4] = lo;
    }
  }

  // qek fill (pre-scaled by SCALE), hi-part only
  for (int nt = wv; nt <= 32; nt += 4) {
    const int r = nt * 16 + ln;
    const int rc = r > 512 ? 512 : r;
    const float* erow = Ek + (size_t)rc * HD + lq * 8;
    const f4 a0 = *(const f4*)&erow[0], a1 = *(const f4*)&erow[4];
    const f4 a2 = *(const f4*)&erow[32], a3 = *(const f4*)&erow[36];
    bfrag e0, e1;
#pragma unroll
    for (int e = 0; e < 4; ++e) {
      e0[e] = (short)f2bf(a0[e]); e0[e + 4] = (short)f2bf(a1[e]);
      e1[e] = (short)f2bf(a2[e]); e1[e + 4] = (short)f2bf(a3[e]);
    }
    f4 acc = {0.f, 0.f, 0.f, 0.f};
    acc = __builtin_amdgcn_mfma_f32_16x16x32_bf16(qh0, e0, acc, 0, 0, 0);
    acc = __builtin_amdgcn_mfma_f32_16x16x32_bf16(qh1, e1, acc, 0, 0, 0);
    if (r < 513) {
#pragma unroll
      for (int rr = 0; rr < 4; ++rr)
        qek_lds[lq * 4 + rr][r] = f2bf(acc[rr] * SCALE);
    }
  }

  const unsigned short* khb = khg + (size_t)bh * SS * HD;
  const unsigned short* klb = klg + (size_t)bh * SS * HD;
  const unsigned short* vtb = VTg + (size_t)bh * HD * SS;
  const int row0 = i0 + lq * 4;
  const int rloc0 = lq * 4;

  // DMA lane constants
  const int rsub = lane >> 3;     // 0..7 within an 8-row chunk
  const int c8d = lane & 7;       // dest 16B slot
  const int r0w = wv * 16;        // wave's private tile rows

  // fragment-read constants
  const int jt = r0w + ln;        // tile row this lane reads (K)
  const int swk = jt & 7;
  const int c8k0 = (lq ^ swk) << 3, c8k1 = ((lq + 4) ^ swk) << 3;

  // prologue: DMA tile 0 into buffer 0 (source pre-swizzled, dest linear)
  {
    const int ra = r0w + rsub, rb2 = r0w + 8 + rsub;
    dma16(khb + ((size_t)ra * HD + ((c8d ^ (ra & 7)) << 3)), &kbh[0][r0w][0]);
    dma16(khb + ((size_t)rb2 * HD + ((c8d ^ (rb2 & 7)) << 3)), &kbh[0][r0w + 8][0]);
    dma16(klb + ((size_t)ra * HD + ((c8d ^ (ra & 7)) << 3)), &kbl[0][r0w][0]);
    dma16(klb + ((size_t)rb2 * HD + ((c8d ^ (rb2 & 7)) << 3)), &kbl[0][r0w + 8][0]);
  }
  __syncthreads();   // qek ready + tile 0 in LDS

  float zz[4] = {0.f, 0.f, 0.f, 0.f};
  float la[4] = {0.f, 0.f, 0.f, 0.f}, ha[4] = {0.f, 0.f, 0.f, 0.f};
  f4 pv = {0.f, 0.f, 0.f, 0.f};   // rows lq*4+r, d = wv*16+ln (unnormalized)

#pragma unroll 1
  for (int it = 0; it < 32; ++it) {
    const int cur = it & 1;
    const int jc = it * 64;
    // issue DMA for tile it+1 into the other buffer (flies behind compute)
    if (it < 31) {
      const int jn = jc + 64;
      const int ra = r0w + rsub, rb2 = r0w + 8 + rsub;
      dma16(khb + ((size_t)(jn + ra) * HD + ((c8d ^ (ra & 7)) << 3)),
            &kbh[cur ^ 1][r0w][0]);
      dma16(khb + ((size_t)(jn + rb2) * HD + ((c8d ^ (rb2 & 7)) << 3)),
            &kbh[cur ^ 1][r0w + 8][0]);
      dma16(klb + ((size_t)(jn + ra) * HD + ((c8d ^ (ra & 7)) << 3)),
            &kbl[cur ^ 1][r0w][0]);
      dma16(klb + ((size_t)(jn + rb2) * HD + ((c8d ^ (rb2 & 7)) << 3)),
            &kbl[cur ^ 1][r0w + 8][0]);
    }
    // V fragments for this tile (L2-resident, long flight to PV)
    const bfrag vb0 = *(const bfrag*)&vtb[(size_t)(r0w + ln) * SS + jc + lq * 8];
    const bfrag vb1 = *(const bfrag*)&vtb[(size_t)(r0w + ln) * SS + jc + 32 + lq * 8];
    // QK^T for this wave's 16-j slice
    const bfrag k0 = *(const bfrag*)&kbh[cur][jt][c8k0];
    const bfrag k1 = *(const bfrag*)&kbh[cur][jt][c8k1];
    const bfrag l0 = *(const bfrag*)&kbl[cur][jt][c8k0];
    const bfrag l1 = *(const bfrag*)&kbl[cur][jt][c8k1];
    f4 acc = {0.f, 0.f, 0.f, 0.f};
    QK6(k0, k1, l0, l1, acc)
    const int j = jc + r0w + ln;
    const int jb2 = j - row0;
#pragma unroll
    for (int r = 0; r < 4; ++r) {
      int idx = jb2 - r + 256;
      idx = idx < 0 ? 0 : (idx > 512 ? 512 : idx);
      const float qv = bf2f(qek_lds[rloc0 + r][idx]);
      const unsigned short eb = f2bf(__expf(fmaf(acc[r], SCALE, qv)));
      const float ef = bf2f(eb);               // rounded e (self-consistent)
      zz[r] += ef;
      e_tile[rloc0 + r][j] = eb;
      const int off = jb2 - r;
      if (off <= -256) la[r] += ef;
      else if (off >= 256) ha[r] += ef;
    }
    __syncthreads();   // e-tile cols ready for PV; DMA(t+1) drained
    // PV: A = e slice (all 16 rows, this tile's 64 j), B = V regs
    const bfrag pa0 = *(const bfrag*)&e_tile[ln][jc + lq * 8];
    const bfrag pa1 = *(const bfrag*)&e_tile[ln][jc + 32 + lq * 8];
    pv = __builtin_amdgcn_mfma_f32_16x16x32_bf16(pa0, vb0, pv, 0, 0, 0);
    pv = __builtin_amdgcn_mfma_f32_16x16x32_bf16(pa1, vb1, pv, 0, 0, 0);
  }

  // merge z and bins within 16-lane groups, publish per wave
#pragma unroll
  for (int r = 0; r < 4; ++r) {
#pragma unroll
    for (int o = 1; o < 16; o <<= 1) {
      zz[r] += __shfl_xor(zz[r], o);
      la[r] += __shfl_xor(la[r], o);
      ha[r] += __shfl_xor(ha[r], o);
    }
  }
  if (ln == 0) {
#pragma unroll
    for (int r = 0; r < 4; ++r) {
      zb[wv][lq * 4 + r] = zz[r];
      lhb[wv][lq * 4 + r][0] = la[r];
      lhb[wv][lq * 4 + r][1] = ha[r];
    }
  }
  __syncthreads();
  float zi[4];
#pragma unroll
  for (int r = 0; r < 4; ++r)
    zi[r] = 1.f / (zb[0][lq * 4 + r] + zb[1][lq * 4 + r] +
                   zb[2][lq * 4 + r] + zb[3][lq * 4 + r]);
  if (t < 16) {
    float bl = 0.f, bhv = 0.f;
#pragma unroll
    for (int q = 0; q < 4; ++q) { bl += lhb[q][t][0]; bhv += lhb[q][t][1]; }
    lhm[t][0] = bl;
    lhm[t][1] = bhv;
  }
  __syncthreads();

  // coalesced NT writeback: w = e * zi; 16 lanes x f4 = 256 B per row
  {
    const int rl = t >> 4;
    const int cin = (t & 15) << 2;
    const float ziw = 1.f / (zb[0][rl] + zb[1][rl] + zb[2][rl] + zb[3][rl]);
    float* arow = attn + ((size_t)bh * SS + i0 + rl) * SS;
#pragma unroll 4
    for (int k = 0; k < 32; ++k) {
      const int col = cin + k * 64;
      const uint2 ev = *(const uint2*)&e_tile[rl][col];
      f4 w;
      w[0] = bf2f((unsigned short)(ev.x & 0xFFFF)) * ziw;
      w[1] = bf2f((unsigned short)(ev.x >> 16)) * ziw;
      w[2] = bf2f((unsigned short)(ev.y & 0xFFFF)) * ziw;
      w[3] = bf2f((unsigned short)(ev.y >> 16)) * ziw;
      __builtin_nontemporal_store(w, (f4*)&arow[col]);
    }
  }

  // band GEMM: A = e band (from e_tile, bins at r=0/512), B = EvT d-slice wv;
  // result + pv, both scaled by row-uniform zi, single concat store.
  {
    f4 acc2 = {0.f, 0.f, 0.f, 0.f};
#pragma unroll 1
    for (int kt = 0; kt < 17; ++kt) {
      bfrag a;
#pragma unroll
      for (int e8 = 0; e8 < 8; ++e8) {
        const int r = kt * 32 + lq * 8 + e8;
        unsigned short v;
        if (r == 0) v = f2bf(lhm[ln][0]);
        else if (r == 512) v = f2bf(lhm[ln][1]);
        else if (r > 512) v = 0;
        else {
          const int j = i0 + ln + r - 256;
          v = ((unsigned)j < SS) ? e_tile[ln][j] : (unsigned short)0;
        }
        a[e8] = (short)v;
      }
      const bfrag bb = *(const bfrag*)&EvT[(size_t)(wv * 16 + ln) * 544 + kt * 32 + lq * 8];
      acc2 = __builtin_amdgcn_mfma_f32_16x16x32_bf16(a, bb, acc2, 0, 0, 0);
    }
#pragma unroll
    for (int r = 0; r < 4; ++r)
      concat[(size_t)(b * SS + i0 + lq * 4 + r) * DM + h * HD + wv * 16 + ln] =
          (pv[r] + acc2[r]) * zi[r];
  }
}

// ---------------------------------------------------------------------------
extern "C" void kernel_launch(void* const* d_in, const int* in_sizes, int n_in,
                              void* d_out, int out_size, void* d_ws, size_t ws_size,
                              hipStream_t stream) {
  (void)in_sizes; (void)n_in; (void)out_size; (void)ws_size;
  const float* query = (const float*)d_in[0];
  const float* value = (const float*)d_in[1];
  const float* Wq = (const float*)d_in[2];
  const float* Wk = (const float*)d_in[3];
  const float* Wv = (const float*)d_in[4];
  const float* Wo = (const float*)d_in[5];
  const float* bo = (const float*)d_in[6];
  const float* Ek = (const float*)d_in[7];
  const float* Ev = (const float*)d_in[8];

  float* out = (float*)d_out;
  float* attn = out + (size_t)SB * SS * DM;

  // workspace carve — 28.1 MB total (proven safe rounds 5-10)
  char* wsb = (char*)d_ws;
  float* Qp = (float*)(wsb + 0);                             //  8 MB
  float* concat = (float*)(wsb + 8388608);                   //  8 MB
  unsigned short* kb16h = (unsigned short*)(wsb + 16777216); //  4 MB
  unsigned short* kb16l = (unsigned short*)(wsb + 20971520); //  4 MB
  unsigned short* VT = (unsigned short*)(wsb + 25165824);    //  4 MB
  unsigned short* EvT = (unsigned short*)(wsb + 29360128);   //  68 KB

  const int M = SB * SS;  // 4096
  dim3 blk(256);
  dim3 ggrid((M / 64) * (DM / 64));  // 512

  gemm_f32<<<ggrid, blk, 0, stream>>>(query, Wq, nullptr, Qp, M, DM, DM);
  gemm_f32_khl<<<ggrid, blk, 0, stream>>>(value, Wk, kb16h, kb16l, M, DM, DM);
  gemm_f32_vt<<<ggrid, blk, 0, stream>>>(value, Wv, VT, M, DM, DM);
  prep_evt<<<136, blk, 0, stream>>>(Ev, EvT);
  fused_attn9<<<2048, blk, 0, stream>>>(Qp, kb16h, kb16l, VT, Ek, EvT, attn, concat);
  gemm_f32<<<ggrid, blk, 0, stream>>>(concat, Wo, bo, out, M, DM, DM);
}

// Round 12
// 382.731 us; speedup vs baseline: 1.2583x; 1.2583x over previous
//
#include <hip/hip_runtime.h>

#define SB 2
#define HH 8
#define SS 2048
#define DM 512
#define HD 64
#define SCALE 0.125f

typedef __attribute__((ext_vector_type(8))) short bfrag;   // 8 x bf16
typedef __attribute__((ext_vector_type(4))) float f4;

static __device__ __forceinline__ unsigned short f2bf(float x) {
  unsigned int u = __float_as_uint(x);
  unsigned int r = (u + 0x7FFFu + ((u >> 16) & 1u)) >> 16;
  return (unsigned short)r;
}
static __device__ __forceinline__ float bf2f(unsigned short s) {
  return __uint_as_float(((unsigned int)s) << 16);
}
static __device__ __forceinline__ void splitf(float x, short& hi, short& lo) {
  const unsigned u = __float_as_uint(x);
  hi = (short)(u >> 16);                                    // truncation
  lo = (short)f2bf(x - __uint_as_float(u & 0xFFFF0000u));   // RTNE residual
}

// async global -> LDS DMA, 16 B per lane (dest = uniform base + lane*16)
static __device__ __forceinline__ void dma16(const unsigned short* g,
                                             unsigned short* l) {
  __builtin_amdgcn_global_load_lds(
      (const __attribute__((address_space(1))) void*)g,
      (__attribute__((address_space(3))) void*)l, 16, 0, 0);
}
static __device__ __forceinline__ void wait_vm4() {
  asm volatile("s_waitcnt vmcnt(4)" ::: "memory");
  __builtin_amdgcn_sched_barrier(0);
}
static __device__ __forceinline__ void wait_vm0() {
  asm volatile("s_waitcnt vmcnt(0)" ::: "memory");
  __builtin_amdgcn_sched_barrier(0);
}

// ---------------- generic fp32 GEMM: C[M][N] = A[M][K] @ B[K][N] (+bias) ---
__global__ __launch_bounds__(256) void gemm_f32(const float* __restrict__ A,
                                                const float* __restrict__ Bm,
                                                const float* __restrict__ bias,
                                                float* __restrict__ C,
                                                int M, int N, int K) {
  __shared__ float As[16][68];
  __shared__ float Bs[16][64];
  const int t = threadIdx.x;
  const int nb = N >> 6;
  const int bm = blockIdx.x / nb, bn = blockIdx.x % nb;
  const int m0 = bm << 6, n0 = bn << 6;
  const int ty = t >> 4, tx = t & 15;
  const int mr = ty << 2, nc = tx << 2;
  const int am = t >> 2, akq = t & 3;
  const int bk = t >> 4, bnq = t & 15;
  float acc[4][4] = {};
  for (int k0 = 0; k0 < K; k0 += 16) {
    const float4 av = *(const float4*)&A[(size_t)(m0 + am) * K + k0 + (akq << 2)];
    const float4 bv = *(const float4*)&Bm[(size_t)(k0 + bk) * N + n0 + (bnq << 2)];
    __syncthreads();
    As[(akq << 2) + 0][am] = av.x;
    As[(akq << 2) + 1][am] = av.y;
    As[(akq << 2) + 2][am] = av.z;
    As[(akq << 2) + 3][am] = av.w;
    *(float4*)&Bs[bk][bnq << 2] = bv;
    __syncthreads();
#pragma unroll
    for (int kk = 0; kk < 16; ++kk) {
      float a[4], b[4];
      *(float4*)a = *(const float4*)&As[kk][mr];
      *(float4*)b = *(const float4*)&Bs[kk][nc];
#pragma unroll
      for (int i = 0; i < 4; ++i)
#pragma unroll
        for (int j = 0; j < 4; ++j) acc[i][j] += a[i] * b[j];
    }
  }
#pragma unroll
  for (int i = 0; i < 4; ++i) {
    float4 v = make_float4(acc[i][0], acc[i][1], acc[i][2], acc[i][3]);
    if (bias) {
      v.x += bias[n0 + nc + 0];
      v.y += bias[n0 + nc + 1];
      v.z += bias[n0 + nc + 2];
      v.w += bias[n0 + nc + 3];
    }
    *(float4*)&C[(size_t)(m0 + mr + i) * N + n0 + nc] = v;
  }
}

// -------- gemm_f32_vt: same compute, epilogue writes per-head transposed ---
__global__ __launch_bounds__(256) void gemm_f32_vt(const float* __restrict__ A,
                                                   const float* __restrict__ Bm,
                                                   unsigned short* __restrict__ VT,
                                                   int M, int N, int K) {
  __shared__ float As[16][68];
  __shared__ float Bs[16][64];
  const int t = threadIdx.x;
  const int nb = N >> 6;
  const int bm = blockIdx.x / nb, bn = blockIdx.x % nb;
  const int m0 = bm << 6, n0 = bn << 6;
  const int ty = t >> 4, tx = t & 15;
  const int mr = ty << 2, nc = tx << 2;
  const int am = t >> 2, akq = t & 3;
  const int bk = t >> 4, bnq = t & 15;
  float acc[4][4] = {};
  for (int k0 = 0; k0 < K; k0 += 16) {
    const float4 av = *(const float4*)&A[(size_t)(m0 + am) * K + k0 + (akq << 2)];
    const float4 bv = *(const float4*)&Bm[(size_t)(k0 + bk) * N + n0 + (bnq << 2)];
    __syncthreads();
    As[(akq << 2) + 0][am] = av.x;
    As[(akq << 2) + 1][am] = av.y;
    As[(akq << 2) + 2][am] = av.z;
    As[(akq << 2) + 3][am] = av.w;
    *(float4*)&Bs[bk][bnq << 2] = bv;
    __syncthreads();
#pragma unroll
    for (int kk = 0; kk < 16; ++kk) {
      float a[4], b[4];
      *(float4*)a = *(const float4*)&As[kk][mr];
      *(float4*)b = *(const float4*)&Bs[kk][nc];
#pragma unroll
      for (int i = 0; i < 4; ++i)
#pragma unroll
        for (int j = 0; j < 4; ++j) acc[i][j] += a[i] * b[j];
    }
  }
#pragma unroll
  for (int i = 0; i < 4; ++i) {
    const int row = m0 + mr + i;
    const int bb = row >> 11, jr = row & 2047;
#pragma unroll
    for (int jx = 0; jx < 4; ++jx) {
      const int col = n0 + nc + jx;
      const int bh = bb * HH + (col >> 6), d = col & 63;
      VT[((size_t)bh * HD + d) * SS + jr] = f2bf(acc[i][jx]);
    }
  }
}

// -------- gemm_f32_khl: K projection, epilogue writes per-head hi/lo bf16 --
__global__ __launch_bounds__(256) void gemm_f32_khl(const float* __restrict__ A,
                                                    const float* __restrict__ Bm,
                                                    unsigned short* __restrict__ kh,
                                                    unsigned short* __restrict__ kl,
                                                    int M, int N, int K) {
  __shared__ float As[16][68];
  __shared__ float Bs[16][64];
  const int t = threadIdx.x;
  const int nb = N >> 6;
  const int bm = blockIdx.x / nb, bn = blockIdx.x % nb;
  const int m0 = bm << 6, n0 = bn << 6;
  const int ty = t >> 4, tx = t & 15;
  const int mr = ty << 2, nc = tx << 2;
  const int am = t >> 2, akq = t & 3;
  const int bk = t >> 4, bnq = t & 15;
  float acc[4][4] = {};
  for (int k0 = 0; k0 < K; k0 += 16) {
    const float4 av = *(const float4*)&A[(size_t)(m0 + am) * K + k0 + (akq << 2)];
    const float4 bv = *(const float4*)&Bm[(size_t)(k0 + bk) * N + n0 + (bnq << 2)];
    __syncthreads();
    As[(akq << 2) + 0][am] = av.x;
    As[(akq << 2) + 1][am] = av.y;
    As[(akq << 2) + 2][am] = av.z;
    As[(akq << 2) + 3][am] = av.w;
    *(float4*)&Bs[bk][bnq << 2] = bv;
    __syncthreads();
#pragma unroll
    for (int kk = 0; kk < 16; ++kk) {
      float a[4], b[4];
      *(float4*)a = *(const float4*)&As[kk][mr];
      *(float4*)b = *(const float4*)&Bs[kk][nc];
#pragma unroll
      for (int i = 0; i < 4; ++i)
#pragma unroll
        for (int j = 0; j < 4; ++j) acc[i][j] += a[i] * b[j];
    }
  }
#pragma unroll
  for (int i = 0; i < 4; ++i) {
    const int row = m0 + mr + i;
    const int bb = row >> 11, jr = row & 2047;
#pragma unroll
    for (int jx = 0; jx < 4; ++jx) {
      const int col = n0 + nc + jx;
      const int bh = bb * HH + (col >> 6), d = col & 63;
      short hi, lo;
      splitf(acc[i][jx], hi, lo);
      const size_t o = ((size_t)bh * SS + jr) * HD + d;
      kh[o] = (unsigned short)hi;
      kl[o] = (unsigned short)lo;
    }
  }
}

// ---------------------------------------------------------------------------
// prep_evt: Ev fp32 [513][64] -> EvT bf16 [64][544] (transposed, zero-padded).
// ---------------------------------------------------------------------------
__global__ void prep_evt(const float* __restrict__ Ev, unsigned short* __restrict__ EvT) {
  const int idx = blockIdx.x * 256 + threadIdx.x;
  if (idx >= 64 * 544) return;
  const int d = idx / 544, r = idx % 544;
  EvT[idx] = (r < 513) ? f2bf(Ev[(size_t)r * HD + d]) : (unsigned short)0;
}

// ---------------------------------------------------------------------------
// fused_attn10: r10 structure + issue-early double-buffered K DMA.
// Sweep 1: NO barriers (wave-private K rows, paced by inline vmcnt(4)).
// Sweep 2: ONE barrier/tile (double-buffered kt/wt/ws; DMA(t+1) issued at
// loop top so the barrier drain is hidden behind QK+exp compute). V read
// direct from L2-resident global. LDS 78.3 KB -> 2 blocks/CU preserved.
// ---------------------------------------------------------------------------
#define QK6(K0, K1, L0, L1, ACC)                                            \
  ACC = __builtin_amdgcn_mfma_f32_16x16x32_bf16(qh0, K0, ACC, 0, 0, 0);     \
  ACC = __builtin_amdgcn_mfma_f32_16x16x32_bf16(qh1, K1, ACC, 0, 0, 0);     \
  ACC = __builtin_amdgcn_mfma_f32_16x16x32_bf16(ql0, K0, ACC, 0, 0, 0);     \
  ACC = __builtin_amdgcn_mfma_f32_16x16x32_bf16(ql1, K1, ACC, 0, 0, 0);     \
  ACC = __builtin_amdgcn_mfma_f32_16x16x32_bf16(qh0, L0, ACC, 0, 0, 0);     \
  ACC = __builtin_amdgcn_mfma_f32_16x16x32_bf16(qh1, L1, ACC, 0, 0, 0);

__global__ __launch_bounds__(256, 2) void fused_attn10(
    const float* __restrict__ Qp,
    const unsigned short* __restrict__ khg,
    const unsigned short* __restrict__ klg,
    const unsigned short* __restrict__ VTg,
    const float* __restrict__ Ek,
    const unsigned short* __restrict__ EvT,
    float* __restrict__ attn,
    float* __restrict__ concat) {
  __shared__ __attribute__((aligned(16))) unsigned short qek_lds[16][520]; // 16640
  __shared__ __attribute__((aligned(16))) unsigned short wband[16][552];   // 17664
  __shared__ __attribute__((aligned(16))) unsigned short kt_h[2][64][64];  // 16384
  __shared__ __attribute__((aligned(16))) unsigned short kt_l[2][64][64];  // 16384
  __shared__ __attribute__((aligned(16))) float ws_tile[2][16][64];        //  8192
  __shared__ __attribute__((aligned(16))) unsigned short wt_bf[2][16][64]; //  4096
  __shared__ float zb[4][16];
  __shared__ float lhb[4][16][2];

  const int t = threadIdx.x;
  const int orig = blockIdx.x;
  const int wg = (orig & 7) * 256 + (orig >> 3);   // XCD swizzle (bijective)
  const int bh = wg >> 7, rb = wg & 127;
  const int b = bh >> 3, h = bh & 7;
  const int wv = t >> 6, lane = t & 63;
  const int ln = lane & 15, lq = lane >> 4;
  const int i0 = rb * 16;

  // zero wband
  {
    unsigned* wz = (unsigned*)&wband[0][0];
    for (int x = t; x < 16 * 552 / 2; x += 256) wz[x] = 0;
  }

  // Q fragments hi/lo (block's 16 rows, same for all waves)
  bfrag qh0, qh1, ql0, ql1;
  {
    const float* qrow = Qp + (size_t)(b * SS + i0 + ln) * DM + h * HD + lq * 8;
    const f4 x0 = *(const f4*)&qrow[0], x1 = *(const f4*)&qrow[4];
    const f4 x2 = *(const f4*)&qrow[32], x3 = *(const f4*)&qrow[36];
#pragma unroll
    for (int e = 0; e < 4; ++e) {
      short hi, lo;
      splitf(x0[e], hi, lo); qh0[e] = hi; ql0[e] = lo;
      splitf(x1[e], hi, lo); qh0[e + 4] = hi; ql0[e + 4] = lo;
      splitf(x2[e], hi, lo); qh1[e] = hi; ql1[e] = lo;
      splitf(x3[e], hi, lo); qh1[e + 4] = hi; ql1[e + 4] = lo;
    }
  }

  const unsigned short* khb = khg + (size_t)bh * SS * HD;
  const unsigned short* klb = klg + (size_t)bh * SS * HD;
  const unsigned short* vtb = VTg + (size_t)bh * HD * SS;
  const int row0 = i0 + lq * 4;
  const int rloc0 = lq * 4;

  // DMA lane constants
  const int rsub = lane >> 3;     // 0..7 within an 8-row chunk
  const int c8d = lane & 7;       // dest 16B slot
  const int r0w = wv * 16;        // wave's private tile rows

  // fragment-read constants
  const int jt = r0w + ln;        // tile row this lane reads (K)
  const int swk = jt & 7;
  const int c8k0 = (lq ^ swk) << 3, c8k1 = ((lq + 4) ^ swk) << 3;

#define ISSUE_K(JC, BUF)                                                      \
  {                                                                           \
    const int ra_ = r0w + rsub, rb_ = r0w + 8 + rsub;                         \
    dma16(khb + ((size_t)((JC) + ra_) * HD + ((c8d ^ (ra_ & 7)) << 3)),       \
          &kt_h[BUF][r0w][0]);                                                \
    dma16(khb + ((size_t)((JC) + rb_) * HD + ((c8d ^ (rb_ & 7)) << 3)),       \
          &kt_h[BUF][r0w + 8][0]);                                            \
    dma16(klb + ((size_t)((JC) + ra_) * HD + ((c8d ^ (ra_ & 7)) << 3)),       \
          &kt_l[BUF][r0w][0]);                                                \
    dma16(klb + ((size_t)((JC) + rb_) * HD + ((c8d ^ (rb_ & 7)) << 3)),       \
          &kt_l[BUF][r0w + 8][0]);                                            \
  }

  // prologue: DMA tile 0 into buffer 0, then qek fill (compute hides DMA)
  ISSUE_K(0, 0)

  // qek fill (pre-scaled by SCALE), hi-part only
  for (int nt = wv; nt <= 32; nt += 4) {
    const int r = nt * 16 + ln;
    const int rc = r > 512 ? 512 : r;
    const float* erow = Ek + (size_t)rc * HD + lq * 8;
    const f4 a0 = *(const f4*)&erow[0], a1 = *(const f4*)&erow[4];
    const f4 a2 = *(const f4*)&erow[32], a3 = *(const f4*)&erow[36];
    bfrag e0, e1;
#pragma unroll
    for (int e = 0; e < 4; ++e) {
      e0[e] = (short)f2bf(a0[e]); e0[e + 4] = (short)f2bf(a1[e]);
      e1[e] = (short)f2bf(a2[e]); e1[e + 4] = (short)f2bf(a3[e]);
    }
    f4 acc = {0.f, 0.f, 0.f, 0.f};
    acc = __builtin_amdgcn_mfma_f32_16x16x32_bf16(qh0, e0, acc, 0, 0, 0);
    acc = __builtin_amdgcn_mfma_f32_16x16x32_bf16(qh1, e1, acc, 0, 0, 0);
    if (r < 513) {
#pragma unroll
      for (int rr = 0; rr < 4; ++rr)
        qek_lds[lq * 4 + rr][r] = f2bf(acc[rr] * SCALE);
    }
  }
  __syncthreads();   // qek + wband-zero + tile-0 DMA ready

  // ---- sweep 1: z only; no barriers (wave-private rows, vmcnt-paced)
  float zz[4] = {0.f, 0.f, 0.f, 0.f};
#pragma unroll 1
  for (int it = 0; it < 32; ++it) {
    const int cur = it & 1;
    if (it < 31) { ISSUE_K((it + 1) * 64, cur ^ 1) wait_vm4(); }
    else wait_vm0();
    const bfrag k0 = *(const bfrag*)&kt_h[cur][jt][c8k0];
    const bfrag k1 = *(const bfrag*)&kt_h[cur][jt][c8k1];
    const bfrag l0 = *(const bfrag*)&kt_l[cur][jt][c8k0];
    const bfrag l1 = *(const bfrag*)&kt_l[cur][jt][c8k1];
    f4 acc = {0.f, 0.f, 0.f, 0.f};
    QK6(k0, k1, l0, l1, acc)
    const int jb2 = it * 64 + r0w + ln - row0;
#pragma unroll
    for (int r = 0; r < 4; ++r) {
      int idx = jb2 - r + 256;
      idx = idx < 0 ? 0 : (idx > 512 ? 512 : idx);
      const float qv = bf2f(qek_lds[rloc0 + r][idx]);
      zz[r] += __expf(fmaf(acc[r], SCALE, qv));
    }
  }
  // issue sweep-2 tile 0 DMA before the merge barrier (overlap)
  ISSUE_K(0, 0)
  // merge z within 16-lane groups, then across waves
#pragma unroll
  for (int r = 0; r < 4; ++r)
#pragma unroll
    for (int o = 1; o < 16; o <<= 1) zz[r] += __shfl_xor(zz[r], o);
  if (ln == 0) {
#pragma unroll
    for (int r = 0; r < 4; ++r) zb[wv][lq * 4 + r] = zz[r];
  }
  __syncthreads();   // z published + sweep-2 tile 0 drained
  float zi[4];
#pragma unroll
  for (int r = 0; r < 4; ++r)
    zi[r] = 1.f / (zb[0][lq * 4 + r] + zb[1][lq * 4 + r] +
                   zb[2][lq * 4 + r] + zb[3][lq * 4 + r]);

  // ---- sweep 2: w (staged), coalesced writeback, band/bins, PV
  f4 pv = {0.f, 0.f, 0.f, 0.f};               // rows lq*4+r, d = wv*16+ln
  float la[4] = {0.f, 0.f, 0.f, 0.f}, ha[4] = {0.f, 0.f, 0.f, 0.f};
  const int wbr = t >> 4;                      // writeback row
  const int wbc = (t & 15) << 2;               // writeback col
#pragma unroll 1
  for (int it = 0; it < 32; ++it) {
    const int cur = it & 1;
    const int jc = it * 64;
    if (it < 31) ISSUE_K(jc + 64, cur ^ 1)     // issue-early, flies behind QK
    // V fragments for this tile (L2-resident; consumed after barrier)
    const bfrag vb0 = *(const bfrag*)&vtb[(size_t)(r0w + ln) * SS + jc + lq * 8];
    const bfrag vb1 = *(const bfrag*)&vtb[(size_t)(r0w + ln) * SS + jc + 32 + lq * 8];
    {
      const bfrag k0 = *(const bfrag*)&kt_h[cur][jt][c8k0];
      const bfrag k1 = *(const bfrag*)&kt_h[cur][jt][c8k1];
      const bfrag l0 = *(const bfrag*)&kt_l[cur][jt][c8k0];
      const bfrag l1 = *(const bfrag*)&kt_l[cur][jt][c8k1];
      f4 acc = {0.f, 0.f, 0.f, 0.f};
      QK6(k0, k1, l0, l1, acc)
      const int j = jc + r0w + ln;
      const int jb2 = j - row0;
#pragma unroll
      for (int r = 0; r < 4; ++r) {
        int idx = jb2 - r + 256;
        idx = idx < 0 ? 0 : (idx > 512 ? 512 : idx);
        const float qv = bf2f(qek_lds[rloc0 + r][idx]);
        const float w = __expf(fmaf(acc[r], SCALE, qv)) * zi[r];
        const int rl = rloc0 + r;
        ws_tile[cur][rl][r0w + ln] = w;
        wt_bf[cur][rl][(((wv * 2 + (ln >> 3)) ^ (rl & 7)) << 3) + (ln & 7)] = f2bf(w);
        const int off = jb2 - r;
        if (off <= -256) la[r] += w;
        else if (off >= 256) ha[r] += w;
        else wband[rl][off + 256] = f2bf(w);
      }
    }
    __syncthreads();   // single barrier: w-tile ready; DMA(t+1) drained
    {  // PV for this wave's d-slice
      const bfrag pa0 = *(const bfrag*)&wt_bf[cur][ln][((lq ^ (ln & 7)) << 3)];
      const bfrag pa1 = *(const bfrag*)&wt_bf[cur][ln][(((4 + lq) ^ (ln & 7)) << 3)];
      pv = __builtin_amdgcn_mfma_f32_16x16x32_bf16(pa0, vb0, pv, 0, 0, 0);
      pv = __builtin_amdgcn_mfma_f32_16x16x32_bf16(pa1, vb1, pv, 0, 0, 0);
      // coalesced NT writeback: 16 lanes x f4 = 256 B per row
      const f4 w4 = *(const f4*)&ws_tile[cur][wbr][wbc];
      __builtin_nontemporal_store(
          w4, (f4*)&attn[((size_t)bh * SS + i0 + wbr) * SS + jc + wbc]);
    }
  }
  // merge boundary bins within 16-lane groups, publish per wave
#pragma unroll
  for (int r = 0; r < 4; ++r) {
#pragma unroll
    for (int o = 1; o < 16; o <<= 1) {
      la[r] += __shfl_xor(la[r], o);
      ha[r] += __shfl_xor(ha[r], o);
    }
  }
  if (ln == 0) {
#pragma unroll
    for (int r = 0; r < 4; ++r) {
      lhb[wv][lq * 4 + r][0] = la[r];
      lhb[wv][lq * 4 + r][1] = ha[r];
    }
  }
  __syncthreads();

  // bins -> wband cols 0 / 512
  if (t < 16) {
    float bl = 0.f, bhv = 0.f;
#pragma unroll
    for (int q = 0; q < 4; ++q) { bl += lhb[q][t][0]; bhv += lhb[q][t][1]; }
    wband[t][0] = f2bf(bl);
    wband[t][512] = f2bf(bhv);
  }
  __syncthreads();

  // band GEMM: wave wv handles d-slice dt = wv; fold into pv and store
  {
    f4 acc2 = {0.f, 0.f, 0.f, 0.f};
#pragma unroll 1
    for (int kt = 0; kt < 17; ++kt) {
      const bfrag a = *(const bfrag*)&wband[ln][kt * 32 + lq * 8];
      const bfrag bb = *(const bfrag*)&EvT[(size_t)(wv * 16 + ln) * 544 + kt * 32 + lq * 8];
      acc2 = __builtin_amdgcn_mfma_f32_16x16x32_bf16(a, bb, acc2, 0, 0, 0);
    }
#pragma unroll
    for (int r = 0; r < 4; ++r)
      concat[(size_t)(b * SS + i0 + lq * 4 + r) * DM + h * HD + wv * 16 + ln] =
          pv[r] + acc2[r];
  }
}

// ---------------------------------------------------------------------------
extern "C" void kernel_launch(void* const* d_in, const int* in_sizes, int n_in,
                              void* d_out, int out_size, void* d_ws, size_t ws_size,
                              hipStream_t stream) {
  (void)in_sizes; (void)n_in; (void)out_size; (void)ws_size;
  const float* query = (const float*)d_in[0];
  const float* value = (const float*)d_in[1];
  const float* Wq = (const float*)d_in[2];
  const float* Wk = (const float*)d_in[3];
  const float* Wv = (const float*)d_in[4];
  const float* Wo = (const float*)d_in[5];
  const float* bo = (const float*)d_in[6];
  const float* Ek = (const float*)d_in[7];
  const float* Ev = (const float*)d_in[8];

  float* out = (float*)d_out;
  float* attn = out + (size_t)SB * SS * DM;

  // workspace carve — 28.1 MB total (proven safe rounds 5-11)
  char* wsb = (char*)d_ws;
  float* Qp = (float*)(wsb + 0);                             //  8 MB
  float* concat = (float*)(wsb + 8388608);                   //  8 MB
  unsigned short* kb16h = (unsigned short*)(wsb + 16777216); //  4 MB
  unsigned short* kb16l = (unsigned short*)(wsb + 20971520); //  4 MB
  unsigned short* VT = (unsigned short*)(wsb + 25165824);    //  4 MB
  unsigned short* EvT = (unsigned short*)(wsb + 29360128);   //  68 KB

  const int M = SB * SS;  // 4096
  dim3 blk(256);
  dim3 ggrid((M / 64) * (DM / 64));  // 512

  gemm_f32<<<ggrid, blk, 0, stream>>>(query, Wq, nullptr, Qp, M, DM, DM);
  gemm_f32_khl<<<ggrid, blk, 0, stream>>>(value, Wk, kb16h, kb16l, M, DM, DM);
  gemm_f32_vt<<<ggrid, blk, 0, stream>>>(value, Wv, VT, M, DM, DM);
  prep_evt<<<136, blk, 0, stream>>>(Ev, EvT);
  fused_attn10<<<2048, blk, 0, stream>>>(Qp, kb16h, kb16l, VT, Ek, EvT, attn, concat);
  gemm_f32<<<ggrid, blk, 0, stream>>>(concat, Wo, bo, out, M, DM, DM);
}

// Round 13
// 315.296 us; speedup vs baseline: 1.5274x; 1.2139x over previous
//
#include <hip/hip_runtime.h>

#define SB 2
#define HH 8
#define SS 2048
#define DM 512
#define HD 64
#define SCALE 0.125f

typedef __attribute__((ext_vector_type(8))) short bfrag;   // 8 x bf16
typedef __attribute__((ext_vector_type(4))) float f4;

static __device__ __forceinline__ unsigned short f2bf(float x) {
  unsigned int u = __float_as_uint(x);
  unsigned int r = (u + 0x7FFFu + ((u >> 16) & 1u)) >> 16;
  return (unsigned short)r;
}
static __device__ __forceinline__ float bf2f(unsigned short s) {
  return __uint_as_float(((unsigned int)s) << 16);
}
static __device__ __forceinline__ void splitf(float x, short& hi, short& lo) {
  const unsigned u = __float_as_uint(x);
  hi = (short)(u >> 16);                                    // truncation
  lo = (short)f2bf(x - __uint_as_float(u & 0xFFFF0000u));   // RTNE residual
}

// async global -> LDS DMA, 16 B per lane (dest = uniform base + lane*16)
static __device__ __forceinline__ void dma16(const unsigned short* g,
                                             unsigned short* l) {
  __builtin_amdgcn_global_load_lds(
      (const __attribute__((address_space(1))) void*)g,
      (__attribute__((address_space(3))) void*)l, 16, 0, 0);
}
static __device__ __forceinline__ void wait_vm4() {
  asm volatile("s_waitcnt vmcnt(4)" ::: "memory");
  __builtin_amdgcn_sched_barrier(0);
}
static __device__ __forceinline__ void wait_vm0() {
  asm volatile("s_waitcnt vmcnt(0)" ::: "memory");
  __builtin_amdgcn_sched_barrier(0);
}

// ---------------------------------------------------------------------------
// prep_w: W[512][512] fp32 -> WT hi/lo bf16 [n][k] (transposed). grid 64/mat.
// (proven r8)
// ---------------------------------------------------------------------------
__global__ __launch_bounds__(256) void prep_w(const float* __restrict__ W,
                                              unsigned short* __restrict__ WTh,
                                              unsigned short* __restrict__ WTl) {
  const int t = threadIdx.x;
  const int kb = blockIdx.x >> 3, nb = blockIdx.x & 7;
  const int k0 = kb * 64 + ((t & 15) << 2);
  const int n0 = nb * 64 + ((t >> 4) << 2);
  f4 m[4];
#pragma unroll
  for (int u = 0; u < 4; ++u) m[u] = *(const f4*)&W[(size_t)(k0 + u) * DM + n0];
#pragma unroll
  for (int c = 0; c < 4; ++c) {
    unsigned short ph[4], pl[4];
#pragma unroll
    for (int u = 0; u < 4; ++u) {
      short hi, lo;
      splitf(m[u][c], hi, lo);
      ph[u] = (unsigned short)hi; pl[u] = (unsigned short)lo;
    }
    const size_t o = (size_t)(n0 + c) * DM + k0;
    *(uint2*)&WTh[o] = make_uint2((unsigned)ph[0] | ((unsigned)ph[1] << 16),
                                  (unsigned)ph[2] | ((unsigned)ph[3] << 16));
    *(uint2*)&WTl[o] = make_uint2((unsigned)pl[0] | ((unsigned)pl[1] << 16),
                                  (unsigned)pl[2] | ((unsigned)pl[3] << 16));
  }
}

// ---------------------------------------------------------------------------
// mm2: C[4096][512] = A[4096][512](fp32) @ W (hi/lo bf16, 3-term split MFMA),
// DMA-staged LDS tiles (r10/r12-proven pattern), 64x64 tile, BK=64, 4 waves.
// mode 0: C = acc (+bias). mode 1: per-head hi/lo bf16 K (O1=kh, O2=kl).
// mode 2: per-head transposed bf16 V (O1=VT). Epilogue formulas = r8-proven.
// ---------------------------------------------------------------------------
__global__ __launch_bounds__(256, 2) void mm2(const float* __restrict__ A,
                                              const unsigned short* __restrict__ WTh,
                                              const unsigned short* __restrict__ WTl,
                                              const float* __restrict__ bias,
                                              float* __restrict__ C,
                                              unsigned short* __restrict__ O1,
                                              unsigned short* __restrict__ O2,
                                              int mode) {
  __shared__ __attribute__((aligned(16))) float As[2][64][64];           // 32 KB
  __shared__ __attribute__((aligned(16))) unsigned short Bhs[2][64][64]; // 16 KB
  __shared__ __attribute__((aligned(16))) unsigned short Bls[2][64][64]; // 16 KB
  const int t = threadIdx.x;
  const int bm = blockIdx.x >> 3, bn = blockIdx.x & 7;
  const int m0 = bm << 6, n0 = bn << 6;
  const int wv = t >> 6, lane = t & 63;
  const int ln = lane & 15, lq = lane >> 4;
  const int mw = (wv & 1) << 5, nw = (wv >> 1) << 5;
  const int a_r = lane >> 4, a_c = lane & 15;   // A DMA: 4 rows/issue
  const int b_r = lane >> 3, b_c = lane & 7;    // B DMA: 8 rows/issue

  // A: f4-granule swizzle key = row&15 (src pre-swizzled, LDS linear)
  // B: 16B-granule swizzle key = row&7
#define MM2_ISSUE(K0, BUF)                                                    \
  {                                                                           \
    _Pragma("unroll")                                                         \
    for (int i = 0; i < 4; ++i) {                                             \
      const int rr = wv * 16 + i * 4 + a_r;                                   \
      dma16((const unsigned short*)(A + (size_t)(m0 + rr) * DM + (K0) +       \
                                    ((a_c ^ (rr & 15)) << 2)),                \
            (unsigned short*)&As[BUF][wv * 16 + i * 4][0]);                   \
    }                                                                         \
    _Pragma("unroll")                                                         \
    for (int i = 0; i < 2; ++i) {                                             \
      const int rr = wv * 16 + i * 8 + b_r;                                   \
      dma16(WTh + (size_t)(n0 + rr) * DM + (K0) + ((b_c ^ (rr & 7)) << 3),    \
            &Bhs[BUF][wv * 16 + i * 8][0]);                                   \
      dma16(WTl + (size_t)(n0 + rr) * DM + (K0) + ((b_c ^ (rr & 7)) << 3),    \
            &Bls[BUF][wv * 16 + i * 8][0]);                                   \
    }                                                                         \
  }

  f4 acc[2][2] = {{{0.f,0.f,0.f,0.f},{0.f,0.f,0.f,0.f}},
                  {{0.f,0.f,0.f,0.f},{0.f,0.f,0.f,0.f}}};

  MM2_ISSUE(0, 0)
  __syncthreads();
#pragma unroll 1
  for (int kt = 0; kt < 8; ++kt) {
    const int cur = kt & 1;
    if (kt < 7) MM2_ISSUE((kt + 1) * 64, cur ^ 1)
#pragma unroll
    for (int ks = 0; ks < 2; ++ks) {
      bfrag ah[2], al[2];
#pragma unroll
      for (int mf = 0; mf < 2; ++mf) {
        const int row = mw + mf * 16 + ln;
        const int cb = ks * 8 + lq * 2;
        const f4 x0 = *(const f4*)&As[cur][row][(cb ^ ln) << 2];
        const f4 x1 = *(const f4*)&As[cur][row][((cb + 1) ^ ln) << 2];
        bfrag h, l2;
#pragma unroll
        for (int e = 0; e < 4; ++e) {
          short hi, lo;
          splitf(x0[e], hi, lo); h[e] = hi; l2[e] = lo;
          splitf(x1[e], hi, lo); h[e + 4] = hi; l2[e + 4] = lo;
        }
        ah[mf] = h; al[mf] = l2;
      }
#pragma unroll
      for (int nf = 0; nf < 2; ++nf) {
        const int nrow = nw + nf * 16 + ln;
        const int s = ((ks * 4 + lq) ^ (ln & 7)) << 3;
        const bfrag bh = *(const bfrag*)&Bhs[cur][nrow][s];
        const bfrag bl = *(const bfrag*)&Bls[cur][nrow][s];
#pragma unroll
        for (int mf = 0; mf < 2; ++mf) {
          acc[mf][nf] = __builtin_amdgcn_mfma_f32_16x16x32_bf16(ah[mf], bh, acc[mf][nf], 0, 0, 0);
          acc[mf][nf] = __builtin_amdgcn_mfma_f32_16x16x32_bf16(ah[mf], bl, acc[mf][nf], 0, 0, 0);
          acc[mf][nf] = __builtin_amdgcn_mfma_f32_16x16x32_bf16(al[mf], bh, acc[mf][nf], 0, 0, 0);
        }
      }
    }
    __syncthreads();
  }

  if (mode == 0) {
#pragma unroll
    for (int mf = 0; mf < 2; ++mf)
#pragma unroll
      for (int nf = 0; nf < 2; ++nf) {
        const int col = n0 + nw + nf * 16 + ln;
        const float bv = bias ? bias[col] : 0.f;
#pragma unroll
        for (int r = 0; r < 4; ++r)
          C[(size_t)(m0 + mw + mf * 16 + lq * 4 + r) * DM + col] =
              acc[mf][nf][r] + bv;
      }
  } else if (mode == 1) {
#pragma unroll
    for (int mf = 0; mf < 2; ++mf)
#pragma unroll
      for (int nf = 0; nf < 2; ++nf) {
        const int col = n0 + nw + nf * 16 + ln;
#pragma unroll
        for (int r = 0; r < 4; ++r) {
          const int row = m0 + mw + mf * 16 + lq * 4 + r;
          const int bb = row >> 11, jr = row & 2047;
          const int bh2 = bb * HH + (col >> 6), d = col & 63;
          short hi, lo;
          splitf(acc[mf][nf][r], hi, lo);
          const size_t o = ((size_t)bh2 * SS + jr) * HD + d;
          O1[o] = (unsigned short)hi;
          O2[o] = (unsigned short)lo;
        }
      }
  } else {
#pragma unroll
    for (int mf = 0; mf < 2; ++mf)
#pragma unroll
      for (int nf = 0; nf < 2; ++nf) {
        const int col = n0 + nw + nf * 16 + ln;
#pragma unroll
        for (int r = 0; r < 4; ++r) {
          const int row = m0 + mw + mf * 16 + lq * 4 + r;
          const int bb = row >> 11, jr = row & 2047;
          const int bh2 = bb * HH + (col >> 6), d = col & 63;
          O1[((size_t)bh2 * HD + d) * SS + jr] = f2bf(acc[mf][nf][r]);
        }
      }
  }
}

// ---------------------------------------------------------------------------
// prep_evt: Ev fp32 [513][64] -> EvT bf16 [64][544] (transposed, zero-padded).
// ---------------------------------------------------------------------------
__global__ void prep_evt(const float* __restrict__ Ev, unsigned short* __restrict__ EvT) {
  const int idx = blockIdx.x * 256 + threadIdx.x;
  if (idx >= 64 * 544) return;
  const int d = idx / 544, r = idx % 544;
  EvT[idx] = (r < 513) ? f2bf(Ev[(size_t)r * HD + d]) : (unsigned short)0;
}

// ---------------------------------------------------------------------------
// fused_attn10 (verbatim r12, proven 265 us / absmax 1.95e-3)
// ---------------------------------------------------------------------------
#define QK6(K0, K1, L0, L1, ACC)                                            \
  ACC = __builtin_amdgcn_mfma_f32_16x16x32_bf16(qh0, K0, ACC, 0, 0, 0);     \
  ACC = __builtin_amdgcn_mfma_f32_16x16x32_bf16(qh1, K1, ACC, 0, 0, 0);     \
  ACC = __builtin_amdgcn_mfma_f32_16x16x32_bf16(ql0, K0, ACC, 0, 0, 0);     \
  ACC = __builtin_amdgcn_mfma_f32_16x16x32_bf16(ql1, K1, ACC, 0, 0, 0);     \
  ACC = __builtin_amdgcn_mfma_f32_16x16x32_bf16(qh0, L0, ACC, 0, 0, 0);     \
  ACC = __builtin_amdgcn_mfma_f32_16x16x32_bf16(qh1, L1, ACC, 0, 0, 0);

__global__ __launch_bounds__(256, 2) void fused_attn10(
    const float* __restrict__ Qp,
    const unsigned short* __restrict__ khg,
    const unsigned short* __restrict__ klg,
    const unsigned short* __restrict__ VTg,
    const float* __restrict__ Ek,
    const unsigned short* __restrict__ EvT,
    float* __restrict__ attn,
    float* __restrict__ concat) {
  __shared__ __attribute__((aligned(16))) unsigned short qek_lds[16][520];
  __shared__ __attribute__((aligned(16))) unsigned short wband[16][552];
  __shared__ __attribute__((aligned(16))) unsigned short kt_h[2][64][64];
  __shared__ __attribute__((aligned(16))) unsigned short kt_l[2][64][64];
  __shared__ __attribute__((aligned(16))) float ws_tile[2][16][64];
  __shared__ __attribute__((aligned(16))) unsigned short wt_bf[2][16][64];
  __shared__ float zb[4][16];
  __shared__ float lhb[4][16][2];

  const int t = threadIdx.x;
  const int orig = blockIdx.x;
  const int wg = (orig & 7) * 256 + (orig >> 3);   // XCD swizzle (bijective)
  const int bh = wg >> 7, rb = wg & 127;
  const int b = bh >> 3, h = bh & 7;
  const int wv = t >> 6, lane = t & 63;
  const int ln = lane & 15, lq = lane >> 4;
  const int i0 = rb * 16;

  {
    unsigned* wz = (unsigned*)&wband[0][0];
    for (int x = t; x < 16 * 552 / 2; x += 256) wz[x] = 0;
  }

  bfrag qh0, qh1, ql0, ql1;
  {
    const float* qrow = Qp + (size_t)(b * SS + i0 + ln) * DM + h * HD + lq * 8;
    const f4 x0 = *(const f4*)&qrow[0], x1 = *(const f4*)&qrow[4];
    const f4 x2 = *(const f4*)&qrow[32], x3 = *(const f4*)&qrow[36];
#pragma unroll
    for (int e = 0; e < 4; ++e) {
      short hi, lo;
      splitf(x0[e], hi, lo); qh0[e] = hi; ql0[e] = lo;
      splitf(x1[e], hi, lo); qh0[e + 4] = hi; ql0[e + 4] = lo;
      splitf(x2[e], hi, lo); qh1[e] = hi; ql1[e] = lo;
      splitf(x3[e], hi, lo); qh1[e + 4] = hi; ql1[e + 4] = lo;
    }
  }

  const unsigned short* khb = khg + (size_t)bh * SS * HD;
  const unsigned short* klb = klg + (size_t)bh * SS * HD;
  const unsigned short* vtb = VTg + (size_t)bh * HD * SS;
  const int row0 = i0 + lq * 4;
  const int rloc0 = lq * 4;

  const int rsub = lane >> 3;
  const int c8d = lane & 7;
  const int r0w = wv * 16;

  const int jt = r0w + ln;
  const int swk = jt & 7;
  const int c8k0 = (lq ^ swk) << 3, c8k1 = ((lq + 4) ^ swk) << 3;

#define ISSUE_K(JC, BUF)                                                      \
  {                                                                           \
    const int ra_ = r0w + rsub, rb_ = r0w + 8 + rsub;                         \
    dma16(khb + ((size_t)((JC) + ra_) * HD + ((c8d ^ (ra_ & 7)) << 3)),       \
          &kt_h[BUF][r0w][0]);                                                \
    dma16(khb + ((size_t)((JC) + rb_) * HD + ((c8d ^ (rb_ & 7)) << 3)),       \
          &kt_h[BUF][r0w + 8][0]);                                            \
    dma16(klb + ((size_t)((JC) + ra_) * HD + ((c8d ^ (ra_ & 7)) << 3)),       \
          &kt_l[BUF][r0w][0]);                                                \
    dma16(klb + ((size_t)((JC) + rb_) * HD + ((c8d ^ (rb_ & 7)) << 3)),       \
          &kt_l[BUF][r0w + 8][0]);                                            \
  }

  ISSUE_K(0, 0)

  for (int nt = wv; nt <= 32; nt += 4) {
    const int r = nt * 16 + ln;
    const int rc = r > 512 ? 512 : r;
    const float* erow = Ek + (size_t)rc * HD + lq * 8;
    const f4 a0 = *(const f4*)&erow[0], a1 = *(const f4*)&erow[4];
    const f4 a2 = *(const f4*)&erow[32], a3 = *(const f4*)&erow[36];
    bfrag e0, e1;
#pragma unroll
    for (int e = 0; e < 4; ++e) {
      e0[e] = (short)f2bf(a0[e]); e0[e + 4] = (short)f2bf(a1[e]);
      e1[e] = (short)f2bf(a2[e]); e1[e + 4] = (short)f2bf(a3[e]);
    }
    f4 acc = {0.f, 0.f, 0.f, 0.f};
    acc = __builtin_amdgcn_mfma_f32_16x16x32_bf16(qh0, e0, acc, 0, 0, 0);
    acc = __builtin_amdgcn_mfma_f32_16x16x32_bf16(qh1, e1, acc, 0, 0, 0);
    if (r < 513) {
#pragma unroll
      for (int rr = 0; rr < 4; ++rr)
        qek_lds[lq * 4 + rr][r] = f2bf(acc[rr] * SCALE);
    }
  }
  __syncthreads();

  float zz[4] = {0.f, 0.f, 0.f, 0.f};
#pragma unroll 1
  for (int it = 0; it < 32; ++it) {
    const int cur = it & 1;
    if (it < 31) { ISSUE_K((it + 1) * 64, cur ^ 1) wait_vm4(); }
    else wait_vm0();
    const bfrag k0 = *(const bfrag*)&kt_h[cur][jt][c8k0];
    const bfrag k1 = *(const bfrag*)&kt_h[cur][jt][c8k1];
    const bfrag l0 = *(const bfrag*)&kt_l[cur][jt][c8k0];
    const bfrag l1 = *(const bfrag*)&kt_l[cur][jt][c8k1];
    f4 acc = {0.f, 0.f, 0.f, 0.f};
    QK6(k0, k1, l0, l1, acc)
    const int jb2 = it * 64 + r0w + ln - row0;
#pragma unroll
    for (int r = 0; r < 4; ++r) {
      int idx = jb2 - r + 256;
      idx = idx < 0 ? 0 : (idx > 512 ? 512 : idx);
      const float qv = bf2f(qek_lds[rloc0 + r][idx]);
      zz[r] += __expf(fmaf(acc[r], SCALE, qv));
    }
  }
  ISSUE_K(0, 0)
#pragma unroll
  for (int r = 0; r < 4; ++r)
#pragma unroll
    for (int o = 1; o < 16; o <<= 1) zz[r] += __shfl_xor(zz[r], o);
  if (ln == 0) {
#pragma unroll
    for (int r = 0; r < 4; ++r) zb[wv][lq * 4 + r] = zz[r];
  }
  __syncthreads();
  float zi[4];
#pragma unroll
  for (int r = 0; r < 4; ++r)
    zi[r] = 1.f / (zb[0][lq * 4 + r] + zb[1][lq * 4 + r] +
                   zb[2][lq * 4 + r] + zb[3][lq * 4 + r]);

  f4 pv = {0.f, 0.f, 0.f, 0.f};
  float la[4] = {0.f, 0.f, 0.f, 0.f}, ha[4] = {0.f, 0.f, 0.f, 0.f};
  const int wbr = t >> 4;
  const int wbc = (t & 15) << 2;
#pragma unroll 1
  for (int it = 0; it < 32; ++it) {
    const int cur = it & 1;
    const int jc = it * 64;
    if (it < 31) ISSUE_K(jc + 64, cur ^ 1)
    const bfrag vb0 = *(const bfrag*)&vtb[(size_t)(r0w + ln) * SS + jc + lq * 8];
    const bfrag vb1 = *(const bfrag*)&vtb[(size_t)(r0w + ln) * SS + jc + 32 + lq * 8];
    {
      const bfrag k0 = *(const bfrag*)&kt_h[cur][jt][c8k0];
      const bfrag k1 = *(const bfrag*)&kt_h[cur][jt][c8k1];
      const bfrag l0 = *(const bfrag*)&kt_l[cur][jt][c8k0];
      const bfrag l1 = *(const bfrag*)&kt_l[cur][jt][c8k1];
      f4 acc = {0.f, 0.f, 0.f, 0.f};
      QK6(k0, k1, l0, l1, acc)
      const int j = jc + r0w + ln;
      const int jb2 = j - row0;
#pragma unroll
      for (int r = 0; r < 4; ++r) {
        int idx = jb2 - r + 256;
        idx = idx < 0 ? 0 : (idx > 512 ? 512 : idx);
        const float qv = bf2f(qek_lds[rloc0 + r][idx]);
        const float w = __expf(fmaf(acc[r], SCALE, qv)) * zi[r];
        const int rl = rloc0 + r;
        ws_tile[cur][rl][r0w + ln] = w;
        wt_bf[cur][rl][(((wv * 2 + (ln >> 3)) ^ (rl & 7)) << 3) + (ln & 7)] = f2bf(w);
        const int off = jb2 - r;
        if (off <= -256) la[r] += w;
        else if (off >= 256) ha[r] += w;
        else wband[rl][off + 256] = f2bf(w);
      }
    }
    __syncthreads();
    {
      const bfrag pa0 = *(const bfrag*)&wt_bf[cur][ln][((lq ^ (ln & 7)) << 3)];
      const bfrag pa1 = *(const bfrag*)&wt_bf[cur][ln][(((4 + lq) ^ (ln & 7)) << 3)];
      pv = __builtin_amdgcn_mfma_f32_16x16x32_bf16(pa0, vb0, pv, 0, 0, 0);
      pv = __builtin_amdgcn_mfma_f32_16x16x32_bf16(pa1, vb1, pv, 0, 0, 0);
      const f4 w4 = *(const f4*)&ws_tile[cur][wbr][wbc];
      __builtin_nontemporal_store(
          w4, (f4*)&attn[((size_t)bh * SS + i0 + wbr) * SS + jc + wbc]);
    }
  }
#pragma unroll
  for (int r = 0; r < 4; ++r) {
#pragma unroll
    for (int o = 1; o < 16; o <<= 1) {
      la[r] += __shfl_xor(la[r], o);
      ha[r] += __shfl_xor(ha[r], o);
    }
  }
  if (ln == 0) {
#pragma unroll
    for (int r = 0; r < 4; ++r) {
      lhb[wv][lq * 4 + r][0] = la[r];
      lhb[wv][lq * 4 + r][1] = ha[r];
    }
  }
  __syncthreads();

  if (t < 16) {
    float bl = 0.f, bhv = 0.f;
#pragma unroll
    for (int q = 0; q < 4; ++q) { bl += lhb[q][t][0]; bhv += lhb[q][t][1]; }
    wband[t][0] = f2bf(bl);
    wband[t][512] = f2bf(bhv);
  }
  __syncthreads();

  {
    f4 acc2 = {0.f, 0.f, 0.f, 0.f};
#pragma unroll 1
    for (int kt = 0; kt < 17; ++kt) {
      const bfrag a = *(const bfrag*)&wband[ln][kt * 32 + lq * 8];
      const bfrag bb = *(const bfrag*)&EvT[(size_t)(wv * 16 + ln) * 544 + kt * 32 + lq * 8];
      acc2 = __builtin_amdgcn_mfma_f32_16x16x32_bf16(a, bb, acc2, 0, 0, 0);
    }
#pragma unroll
    for (int r = 0; r < 4; ++r)
      concat[(size_t)(b * SS + i0 + lq * 4 + r) * DM + h * HD + wv * 16 + ln] =
          pv[r] + acc2[r];
  }
}

// ---------------------------------------------------------------------------
extern "C" void kernel_launch(void* const* d_in, const int* in_sizes, int n_in,
                              void* d_out, int out_size, void* d_ws, size_t ws_size,
                              hipStream_t stream) {
  (void)in_sizes; (void)n_in; (void)out_size; (void)ws_size;
  const float* query = (const float*)d_in[0];
  const float* value = (const float*)d_in[1];
  const float* Wq = (const float*)d_in[2];
  const float* Wk = (const float*)d_in[3];
  const float* Wv = (const float*)d_in[4];
  const float* Wo = (const float*)d_in[5];
  const float* bo = (const float*)d_in[6];
  const float* Ek = (const float*)d_in[7];
  const float* Ev = (const float*)d_in[8];

  float* out = (float*)d_out;
  float* attn = out + (size_t)SB * SS * DM;

  // workspace carve — 33.62 MB total (33.82 MB proven safe in round 1)
  char* wsb = (char*)d_ws;
  float* Qp = (float*)(wsb + 0);                             //  8 MB
  float* concat = (float*)(wsb + 8388608);                   //  8 MB
  unsigned short* kb16h = (unsigned short*)(wsb + 16777216); //  4 MB
  unsigned short* kb16l = (unsigned short*)(wsb + 20971520); //  4 MB
  unsigned short* VT = (unsigned short*)(wsb + 25165824);    //  4 MB
  unsigned short* EvT = (unsigned short*)(wsb + 29360128);   //  68 KB
  unsigned short* WTs = (unsigned short*)(wsb + 29491200);   //  4 MB (8x512KB)
  unsigned short* WTqh = WTs + 0 * 262144;
  unsigned short* WTql = WTs + 1 * 262144;
  unsigned short* WTkh = WTs + 2 * 262144;
  unsigned short* WTkl = WTs + 3 * 262144;
  unsigned short* WTvh = WTs + 4 * 262144;
  unsigned short* WTvl = WTs + 5 * 262144;
  unsigned short* WToh = WTs + 6 * 262144;
  unsigned short* WTol = WTs + 7 * 262144;

  dim3 blk(256);

  prep_w<<<64, blk, 0, stream>>>(Wq, WTqh, WTql);
  prep_w<<<64, blk, 0, stream>>>(Wk, WTkh, WTkl);
  prep_w<<<64, blk, 0, stream>>>(Wv, WTvh, WTvl);
  prep_w<<<64, blk, 0, stream>>>(Wo, WToh, WTol);
  prep_evt<<<136, blk, 0, stream>>>(Ev, EvT);
  mm2<<<512, blk, 0, stream>>>(query, WTqh, WTql, nullptr, Qp, nullptr, nullptr, 0);
  mm2<<<512, blk, 0, stream>>>(value, WTkh, WTkl, nullptr, nullptr, kb16h, kb16l, 1);
  mm2<<<512, blk, 0, stream>>>(value, WTvh, WTvl, nullptr, nullptr, VT, nullptr, 2);
  fused_attn10<<<2048, blk, 0, stream>>>(Qp, kb16h, kb16l, VT, Ek, EvT, attn, concat);
  mm2<<<512, blk, 0, stream>>>(concat, WToh, WTol, bo, out, nullptr, nullptr, 0);
}